// Round 5
// baseline (1687.774 us; speedup 1.0000x reference)
//
#include <hip/hip_runtime.h>
#include <stdint.h>

// FusedGPTQMLP on MI355X (gfx950).
// Round 5: dtype fix — reference fp16 tensors arrive as FLOAT32 (harness
// canonicalizes non-bf16 floats to fp32: "else float*"). x/scales read as
// fp32; output written as fp32. Internal compute: bf16 MFMA (m97 family),
// boring uint4 reg-staging (kept from round 4 for clean attribution).
// ws: xb [M,HIDDEN] bf16 | gi [MC,INTER] bf16 | wb weight chunk (adaptive).

#define HIDDEN 4096
#define INTER  11008
#define BM 128
#define BN 128
#define BK 64

typedef __bf16 bf16x8 __attribute__((ext_vector_type(8)));
typedef float f32x4 __attribute__((ext_vector_type(4)));

__device__ __forceinline__ ushort f2bf_rne(float f) {
  uint32_t u = __float_as_uint(f);
  u += 0x7FFFu + ((u >> 16) & 1u);
  return (ushort)(u >> 16);
}

__device__ __forceinline__ float bf2f(ushort h) {
  return __uint_as_float(((uint32_t)h) << 16);
}

// fp32 -> bf16 bulk convert, 4 elements/thread.
__global__ void f32_to_bf16_kernel(const float* __restrict__ src,
                                   ushort* __restrict__ dst, int n4) {
  const int i = blockIdx.x * 256 + threadIdx.x;
  if (i < n4) {
    const float4 v = ((const float4*)src)[i];
    ushort4 o;
    o.x = f2bf_rne(v.x); o.y = f2bf_rne(v.y);
    o.z = f2bf_rne(v.z); o.w = f2bf_rne(v.w);
    ((ushort4*)dst)[i] = o;
  }
}

// Dequant qweight[k8][n] (8 k-nibbles per int32) into packet layout:
// Bp[(k8*nc + n_local)*8 + j] = W[k8*8+j][n0+n_local], bf16. Scales are fp32.
__global__ void dequant_kernel(const int32_t* __restrict__ qw,
                               const float* __restrict__ sc,
                               const int32_t* __restrict__ zr,
                               ushort* __restrict__ Bp,
                               int Nfull, int n0, int nc) {
  const int n_local = blockIdx.x * 128 + threadIdx.x;
  const int k8 = blockIdx.y;
  const int n = n0 + n_local;
  const int g = k8 >> 4;  // groupsize 128 => 16 k8-rows per group
  const uint32_t q = (uint32_t)qw[(size_t)k8 * Nfull + n];
  const float s = sc[(size_t)g * Nfull + n];
  const uint32_t zv = (uint32_t)zr[(size_t)g * (Nfull >> 3) + (n >> 3)];
  const int z1 = (int)((zv >> ((n & 7) * 4)) & 15u) + 1;
  union { ushort h[8]; uint4 v; } o;
#pragma unroll
  for (int j = 0; j < 8; j++) {
    const int qi = (int)((q >> (4 * j)) & 15u) - z1;  // (q - (z+1)), exact int
    o.h[j] = f2bf_rne((float)qi * s);
  }
  *(uint4*)(Bp + ((size_t)k8 * nc + n_local) * 8) = o.v;
}

// C[m, n] = A[m, :] @ W[:, n] over this chunk's nc columns.
// A: bf16 [rows, lda] (pre-offset). Bp: packets [K/8][nc][8] bf16.
// MODE 0: C bf16 = result. MODE 1: C bf16 = silu(C_old) * result (SwiGLU).
// MODE 2: C fp32 = result (final output).
template <int MODE>
__global__ void gemm_bt_kernel(const ushort* __restrict__ A,
                               const ushort* __restrict__ Bp,
                               void* __restrict__ Cv,
                               int K, int nc, int lda, int ldc) {
  __shared__ ushort sA[BM * BK];           // [m][k] row-major, 16 KB
  __shared__ ushort sB[(BK / 8) * BN * 8]; // [p][n][8] packets, 16 KB

  const int tid = threadIdx.x;
  const int w = tid >> 6;
  const int lane = tid & 63;
  const int l16 = lane & 15;
  const int quad = lane >> 4;
  const int wm = (w >> 1) * 64;
  const int wn = (w & 1) * 64;
  const int m0 = blockIdx.y * BM;
  const int bn0 = blockIdx.x * BN;

  f32x4 acc[4][4];
#pragma unroll
  for (int i = 0; i < 4; i++)
#pragma unroll
    for (int j = 0; j < 4; j++)
      acc[i][j] = (f32x4){0.0f, 0.0f, 0.0f, 0.0f};

  for (int kt = 0; kt < K; kt += BK) {
    const int kp0 = kt >> 3;
    __syncthreads();
    // Boring staging: 256 threads x 4 x uint4 each for A and B.
    // sA uint4 index u: row = u>>3, k-packet = u&7 (dest = u*8 ushorts).
    // sB uint4 index u: packet-row = u>>7, col = u&127 (dest = u*8 ushorts).
#pragma unroll
    for (int r = 0; r < 4; r++) {
      const int u = r * 256 + tid;
      const int am = u >> 3, apk = u & 7;
      const uint4 va = *(const uint4*)(A + (size_t)(m0 + am) * lda + kt + apk * 8);
      *(uint4*)(sA + (size_t)u * 8) = va;
      const int bp = u >> 7, bn = u & 127;
      const uint4 vb = *(const uint4*)(Bp + ((size_t)(kp0 + bp) * nc + bn0 + bn) * 8);
      *(uint4*)(sB + (size_t)u * 8) = vb;
    }
    __syncthreads();

#pragma unroll
    for (int kk = 0; kk < 2; kk++) {
      bf16x8 af[4], bfr[4];
#pragma unroll
      for (int i = 0; i < 4; i++)
        af[i] = *(const bf16x8*)(sA + (wm + i * 16 + l16) * 64 + kk * 32 + quad * 8);
#pragma unroll
      for (int j = 0; j < 4; j++)
        bfr[j] = *(const bf16x8*)(sB + ((kk * 4 + quad) * 128 + wn + j * 16 + l16) * 8);
#pragma unroll
      for (int i = 0; i < 4; i++)
#pragma unroll
        for (int j = 0; j < 4; j++)
          acc[i][j] = __builtin_amdgcn_mfma_f32_16x16x32_bf16(af[i], bfr[j], acc[i][j], 0, 0, 0);
    }
  }

  // Epilogue. C/D layout: col = lane&15, row = quad*4 + reg.
#pragma unroll
  for (int i = 0; i < 4; i++) {
#pragma unroll
    for (int r = 0; r < 4; r++) {
      const int gm = m0 + wm + i * 16 + quad * 4 + r;
#pragma unroll
      for (int j = 0; j < 4; j++) {
        float v = acc[i][j][r];
        const int cn = j * 16 + l16;
        if (MODE == 2) {
          float* crow = (float*)Cv + (size_t)gm * ldc + bn0 + wn;
          crow[cn] = v;
        } else {
          ushort* crow = (ushort*)Cv + (size_t)gm * ldc + bn0 + wn;
          if (MODE == 1) {
            const float gv = bf2f(crow[cn]);             // gate (bf16)
            v = (gv / (1.0f + __expf(-gv))) * v;         // silu(gate) * up
          }
          crow[cn] = f2bf_rne(v);
        }
      }
    }
  }
}

extern "C" void kernel_launch(void* const* d_in, const int* in_sizes, int n_in,
                              void* d_out, int out_size, void* d_ws, size_t ws_size,
                              hipStream_t stream) {
  (void)n_in; (void)out_size;
  const float*   x   = (const float*)d_in[0];    // fp32 [4096, 4096]
  const int32_t* gq  = (const int32_t*)d_in[1];  // [512, 11008]
  const float*   gs  = (const float*)d_in[2];    // fp32 [32, 11008]
  const int32_t* gz  = (const int32_t*)d_in[3];  // [32, 1376]
  const int32_t* uq  = (const int32_t*)d_in[4];
  const float*   us  = (const float*)d_in[5];
  const int32_t* uz  = (const int32_t*)d_in[6];
  const int32_t* dq  = (const int32_t*)d_in[7];  // [1376, 4096]
  const float*   dsc = (const float*)d_in[8];    // fp32 [86, 4096]
  const int32_t* dz  = (const int32_t*)d_in[9];  // [86, 512]
  float* outp = (float*)d_out;                   // fp32 [4096, 4096]

  const int M = in_sizes[0] / HIDDEN;            // 4096

  // ---- ws-size-adaptive plan (all scratch strictly inside d_ws) ----
  const size_t W = ws_size;
  const size_t col12 = (size_t)HIDDEN * 2;   // 8192 B per dequant col (K=HIDDEN)
  const size_t col3  = (size_t)INTER * 2;    // 22016 B per dequant col (K=INTER)
  const size_t xb_bytes = (size_t)M * HIDDEN * 2;   // 33.5 MB
  int MC = 128;
  for (int cand = M; cand >= 128; cand >>= 1) {
    if (xb_bytes + (size_t)cand * INTER * 2 + col3 * 128 <= W) { MC = cand; break; }
  }
  ushort* xb = (ushort*)d_ws;                              // [M, HIDDEN] bf16
  ushort* gi = xb + (size_t)M * HIDDEN;                    // [MC, INTER] bf16
  ushort* wb = gi + (size_t)MC * INTER;                    // weight chunk
  const size_t used = xb_bytes + (size_t)MC * INTER * 2;
  const size_t wbuf = (W > used) ? W - used : 0;
  int NC12 = (int)(wbuf / col12); NC12 &= ~127;
  if (NC12 < 128) NC12 = 128;
  if (NC12 > 2816) NC12 = 2816;
  int NC3 = (int)(wbuf / col3); NC3 &= ~127;
  if (NC3 < 128) NC3 = 128;
  if (NC3 > 2048) NC3 = 2048;

  // Convert x (fp32) -> xb (bf16) once.
  const int n4 = M * HIDDEN / 4;
  f32_to_bf16_kernel<<<(n4 + 255) / 256, 256, 0, stream>>>(x, xb, n4);

  for (int m0 = 0; m0 < M; m0 += MC) {
    const ushort* xm = xb + (size_t)m0 * HIDDEN;
    // Phase 1: gate = x @ Wg   (into gi, bf16)
    for (int n0 = 0; n0 < INTER; ) {
      int nc = INTER - n0; if (nc > NC12) nc = NC12;
      dequant_kernel<<<dim3(nc / 128, HIDDEN / 8), 128, 0, stream>>>(
          gq, gs, gz, wb, INTER, n0, nc);
      gemm_bt_kernel<0><<<dim3(nc / BN, MC / BM), 256, 0, stream>>>(
          xm, wb, gi + n0, HIDDEN, nc, HIDDEN, INTER);
      n0 += nc;
    }
    // Phase 2: inter = silu(gate) * (x @ Wu)   (in place over gi)
    for (int n0 = 0; n0 < INTER; ) {
      int nc = INTER - n0; if (nc > NC12) nc = NC12;
      dequant_kernel<<<dim3(nc / 128, HIDDEN / 8), 128, 0, stream>>>(
          uq, us, uz, wb, INTER, n0, nc);
      gemm_bt_kernel<1><<<dim3(nc / BN, MC / BM), 256, 0, stream>>>(
          xm, wb, gi + n0, HIDDEN, nc, HIDDEN, INTER);
      n0 += nc;
    }
    // Phase 3: out = inter @ Wd   (fp32 out)
    for (int n0 = 0; n0 < HIDDEN; ) {
      int nc = HIDDEN - n0; if (nc > NC3) nc = NC3;
      dequant_kernel<<<dim3(nc / 128, INTER / 8), 128, 0, stream>>>(
          dq, dsc, dz, wb, HIDDEN, n0, nc);
      gemm_bt_kernel<2><<<dim3(nc / BN, MC / BM), 256, 0, stream>>>(
          gi, wb, (void*)(outp + (size_t)m0 * HIDDEN + n0), INTER, nc, INTER, HIDDEN);
      n0 += nc;
    }
  }
}

// Round 6
// 1474.585 us; speedup vs baseline: 1.1446x; 1.1446x over previous
//
#include <hip/hip_runtime.h>
#include <stdint.h>

// FusedGPTQMLP on MI355X (gfx950).
// Round 6: restore global_load_lds (width=16) staging + XOR bank swizzle on
// the A tile. Inputs: x/scales fp32 (harness canonicalizes fp16->fp32),
// output fp32. Internal compute: bf16 MFMA, 128x128x64 tiles (m97 family).
// ws: xb [M,HIDDEN] bf16 | gi [MC,INTER] bf16 | wb weight chunk (adaptive).

#define HIDDEN 4096
#define INTER  11008
#define BM 128
#define BN 128
#define BK 64

typedef __bf16 bf16x8 __attribute__((ext_vector_type(8)));
typedef float f32x4 __attribute__((ext_vector_type(4)));

__device__ __forceinline__ ushort f2bf_rne(float f) {
  uint32_t u = __float_as_uint(f);
  u += 0x7FFFu + ((u >> 16) & 1u);
  return (ushort)(u >> 16);
}

__device__ __forceinline__ float bf2f(ushort h) {
  return __uint_as_float(((uint32_t)h) << 16);
}

// fp32 -> bf16 bulk convert, 4 elements/thread.
__global__ void f32_to_bf16_kernel(const float* __restrict__ src,
                                   ushort* __restrict__ dst, int n4) {
  const int i = blockIdx.x * 256 + threadIdx.x;
  if (i < n4) {
    const float4 v = ((const float4*)src)[i];
    ushort4 o;
    o.x = f2bf_rne(v.x); o.y = f2bf_rne(v.y);
    o.z = f2bf_rne(v.z); o.w = f2bf_rne(v.w);
    ((ushort4*)dst)[i] = o;
  }
}

// Dequant qweight[k8][n] (8 k-nibbles per int32) into packet layout:
// Bp[(k8*nc + n_local)*8 + j] = W[k8*8+j][n0+n_local], bf16. Scales fp32.
__global__ void dequant_kernel(const int32_t* __restrict__ qw,
                               const float* __restrict__ sc,
                               const int32_t* __restrict__ zr,
                               ushort* __restrict__ Bp,
                               int Nfull, int n0, int nc) {
  const int n_local = blockIdx.x * 128 + threadIdx.x;
  const int k8 = blockIdx.y;
  const int n = n0 + n_local;
  const int g = k8 >> 4;  // groupsize 128 => 16 k8-rows per group
  const uint32_t q = (uint32_t)qw[(size_t)k8 * Nfull + n];
  const float s = sc[(size_t)g * Nfull + n];
  const uint32_t zv = (uint32_t)zr[(size_t)g * (Nfull >> 3) + (n >> 3)];
  const int z1 = (int)((zv >> ((n & 7) * 4)) & 15u) + 1;
  union { ushort h[8]; uint4 v; } o;
#pragma unroll
  for (int j = 0; j < 8; j++) {
    const int qi = (int)((q >> (4 * j)) & 15u) - z1;  // (q - (z+1)), exact int
    o.h[j] = f2bf_rne((float)qi * s);
  }
  *(uint4*)(Bp + ((size_t)k8 * nc + n_local) * 8) = o.v;
}

// C[m, n] = A[m, :] @ W[:, n] over this chunk's nc columns.
// A: bf16 [rows, lda] (pre-offset). Bp: packets [K/8][nc][8] bf16.
// MODE 0: C bf16 = result. MODE 1: C bf16 = silu(C_old) * result (SwiGLU).
// MODE 2: C fp32 = result (final output).
// sA holds packet p of row m at column (p ^ (m&7)) -- XOR bank swizzle.
template <int MODE>
__global__ void gemm_bt_kernel(const ushort* __restrict__ A,
                               const ushort* __restrict__ Bp,
                               void* __restrict__ Cv,
                               int K, int nc, int lda, int ldc) {
  __shared__ ushort sA[BM * BK];           // [m][pk^swz][8], 16 KB
  __shared__ ushort sB[(BK / 8) * BN * 8]; // [p][n][8] packets, 16 KB

  const int tid = threadIdx.x;
  const int w = tid >> 6;
  const int lane = tid & 63;
  const int l16 = lane & 15;
  const int quad = lane >> 4;
  const int wm = (w >> 1) * 64;
  const int wn = (w & 1) * 64;
  const int m0 = blockIdx.y * BM;
  const int bn0 = blockIdx.x * BN;

  const int arow = tid >> 3;          // 0..31 (row within 32-row slab)
  const int apk = (tid & 7) ^ (arow & 7);  // swizzled source packet
  const int bprow = tid >> 7;         // 0..1 (packet-row within 2-row slab)
  const int bcol = tid & 127;

  f32x4 acc[4][4];
#pragma unroll
  for (int i = 0; i < 4; i++)
#pragma unroll
    for (int j = 0; j < 4; j++)
      acc[i][j] = (f32x4){0.0f, 0.0f, 0.0f, 0.0f};

  for (int kt = 0; kt < K; kt += BK) {
    const int kp0 = kt >> 3;
    __syncthreads();
    // A tile [128][64] via async global->LDS width 16 (wave-uniform base,
    // lane i lands at base + i*16). Lane's global packet is XOR-permuted
    // within its 128B row segment -> swizzled LDS layout, coalescing intact.
#pragma unroll
    for (int r = 0; r < 4; r++) {
      const ushort* ga = A + (size_t)(m0 + r * 32 + arow) * lda + kt + apk * 8;
      __builtin_amdgcn_global_load_lds(
          (const __attribute__((address_space(1))) uint32_t*)ga,
          (__attribute__((address_space(3))) uint32_t*)(sA + r * 2048 + w * 512),
          16, 0, 0);
    }
    // B tile: 8 packet-rows x 128 cols, straight copy of packet layout.
#pragma unroll
    for (int r = 0; r < 4; r++) {
      const ushort* gb = Bp + ((size_t)(kp0 + r * 2 + bprow) * nc + bn0 + bcol) * 8;
      __builtin_amdgcn_global_load_lds(
          (const __attribute__((address_space(1))) uint32_t*)gb,
          (__attribute__((address_space(3))) uint32_t*)(sB + r * 2048 + w * 512),
          16, 0, 0);
    }
    __syncthreads();  // drains vmcnt -> LDS valid

#pragma unroll
    for (int kk = 0; kk < 2; kk++) {
      bf16x8 af[4], bfr[4];
#pragma unroll
      for (int i = 0; i < 4; i++) {
        const int am = wm + i * 16 + l16;
        af[i] = *(const bf16x8*)(sA + am * 64 + (((kk * 4 + quad) ^ (am & 7)) * 8));
      }
#pragma unroll
      for (int j = 0; j < 4; j++)
        bfr[j] = *(const bf16x8*)(sB + ((kk * 4 + quad) * 128 + wn + j * 16 + l16) * 8);
#pragma unroll
      for (int i = 0; i < 4; i++)
#pragma unroll
        for (int j = 0; j < 4; j++)
          acc[i][j] = __builtin_amdgcn_mfma_f32_16x16x32_bf16(af[i], bfr[j], acc[i][j], 0, 0, 0);
    }
  }

  // Epilogue. C/D layout: col = lane&15, row = quad*4 + reg.
#pragma unroll
  for (int i = 0; i < 4; i++) {
#pragma unroll
    for (int r = 0; r < 4; r++) {
      const int gm = m0 + wm + i * 16 + quad * 4 + r;
#pragma unroll
      for (int j = 0; j < 4; j++) {
        float v = acc[i][j][r];
        const int cn = j * 16 + l16;
        if (MODE == 2) {
          float* crow = (float*)Cv + (size_t)gm * ldc + bn0 + wn;
          crow[cn] = v;
        } else {
          ushort* crow = (ushort*)Cv + (size_t)gm * ldc + bn0 + wn;
          if (MODE == 1) {
            const float gv = bf2f(crow[cn]);             // gate (bf16)
            v = (gv / (1.0f + __expf(-gv))) * v;         // silu(gate) * up
          }
          crow[cn] = f2bf_rne(v);
        }
      }
    }
  }
}

extern "C" void kernel_launch(void* const* d_in, const int* in_sizes, int n_in,
                              void* d_out, int out_size, void* d_ws, size_t ws_size,
                              hipStream_t stream) {
  (void)n_in; (void)out_size;
  const float*   x   = (const float*)d_in[0];    // fp32 [4096, 4096]
  const int32_t* gq  = (const int32_t*)d_in[1];  // [512, 11008]
  const float*   gs  = (const float*)d_in[2];    // fp32 [32, 11008]
  const int32_t* gz  = (const int32_t*)d_in[3];  // [32, 1376]
  const int32_t* uq  = (const int32_t*)d_in[4];
  const float*   us  = (const float*)d_in[5];
  const int32_t* uz  = (const int32_t*)d_in[6];
  const int32_t* dq  = (const int32_t*)d_in[7];  // [1376, 4096]
  const float*   dsc = (const float*)d_in[8];    // fp32 [86, 4096]
  const int32_t* dz  = (const int32_t*)d_in[9];  // [86, 512]
  float* outp = (float*)d_out;                   // fp32 [4096, 4096]

  const int M = in_sizes[0] / HIDDEN;            // 4096

  // ---- ws-size-adaptive plan (all scratch strictly inside d_ws) ----
  const size_t W = ws_size;
  const size_t col12 = (size_t)HIDDEN * 2;   // 8192 B per dequant col (K=HIDDEN)
  const size_t col3  = (size_t)INTER * 2;    // 22016 B per dequant col (K=INTER)
  const size_t xb_bytes = (size_t)M * HIDDEN * 2;   // 33.5 MB
  int MC = 128;
  for (int cand = M; cand >= 128; cand >>= 1) {
    if (xb_bytes + (size_t)cand * INTER * 2 + col3 * 128 <= W) { MC = cand; break; }
  }
  ushort* xb = (ushort*)d_ws;                              // [M, HIDDEN] bf16
  ushort* gi = xb + (size_t)M * HIDDEN;                    // [MC, INTER] bf16
  ushort* wb = gi + (size_t)MC * INTER;                    // weight chunk
  const size_t used = xb_bytes + (size_t)MC * INTER * 2;
  const size_t wbuf = (W > used) ? W - used : 0;
  int NC12 = (int)(wbuf / col12); NC12 &= ~127;
  if (NC12 < 128) NC12 = 128;
  if (NC12 > INTER) NC12 = INTER;            // 11008 = 86*128
  int NC3 = (int)(wbuf / col3); NC3 &= ~127;
  if (NC3 < 128) NC3 = 128;
  if (NC3 > HIDDEN) NC3 = HIDDEN;

  // Convert x (fp32) -> xb (bf16) once.
  const int n4 = M * HIDDEN / 4;
  f32_to_bf16_kernel<<<(n4 + 255) / 256, 256, 0, stream>>>(x, xb, n4);

  for (int m0 = 0; m0 < M; m0 += MC) {
    const ushort* xm = xb + (size_t)m0 * HIDDEN;
    // Phase 1: gate = x @ Wg   (into gi, bf16)
    for (int n0 = 0; n0 < INTER; ) {
      int nc = INTER - n0; if (nc > NC12) nc = NC12;
      dequant_kernel<<<dim3(nc / 128, HIDDEN / 8), 128, 0, stream>>>(
          gq, gs, gz, wb, INTER, n0, nc);
      gemm_bt_kernel<0><<<dim3(nc / BN, MC / BM), 256, 0, stream>>>(
          xm, wb, gi + n0, HIDDEN, nc, HIDDEN, INTER);
      n0 += nc;
    }
    // Phase 2: inter = silu(gate) * (x @ Wu)   (in place over gi)
    for (int n0 = 0; n0 < INTER; ) {
      int nc = INTER - n0; if (nc > NC12) nc = NC12;
      dequant_kernel<<<dim3(nc / 128, HIDDEN / 8), 128, 0, stream>>>(
          uq, us, uz, wb, INTER, n0, nc);
      gemm_bt_kernel<1><<<dim3(nc / BN, MC / BM), 256, 0, stream>>>(
          xm, wb, gi + n0, HIDDEN, nc, HIDDEN, INTER);
      n0 += nc;
    }
    // Phase 3: out = inter @ Wd   (fp32 out)
    for (int n0 = 0; n0 < HIDDEN; ) {
      int nc = HIDDEN - n0; if (nc > NC3) nc = NC3;
      dequant_kernel<<<dim3(nc / 128, INTER / 8), 128, 0, stream>>>(
          dq, dsc, dz, wb, HIDDEN, n0, nc);
      gemm_bt_kernel<2><<<dim3(nc / BN, MC / BM), 256, 0, stream>>>(
          gi, wb, (void*)(outp + (size_t)m0 * HIDDEN + n0), INTER, nc, INTER, HIDDEN);
      n0 += nc;
    }
  }
}